// Round 11
// baseline (103.072 us; speedup 1.0000x reference)
//
#include <hip/hip_runtime.h>

typedef float v2f __attribute__((ext_vector_type(2)));
typedef float v4f __attribute__((ext_vector_type(4)));

#define IMG 512
#define TS  32
#define NBLK 2048             // 1 tile per block: 16x16 tiles x 8 images

// LDS layouts (floats)
#define A_STR  58             // h tile [52][58]; gy=y0-10+r, gx=x0-12+c (cols 0..55)
#define BT_STR 46             // BT [56][46]: BT[c][by], by 0..41 (gy=y0-5+by)
#define ET_STR 44             // ET [42][44]: ET[ex][ey] (transposed E); overlays Abuf
#define CT_STR 36             // CT [42][36]: CT[ex][oy], oy 0..31; overlays Bbuf

__device__ __forceinline__ v2f lo2(v4f v) { return __builtin_shufflevector(v, v, 0, 1); }
__device__ __forceinline__ v2f hi2(v4f v) { return __builtin_shufflevector(v, v, 2, 3); }

// one float4 of the h halo tile (zero-padded), quad index idx in [0,728)
__device__ __forceinline__ v4f ldq(const float* __restrict__ hmap, size_t base,
                                   int x0, int y0, int idx) {
    int r = idx / 14, q = idx - r * 14;
    int gy = y0 - 10 + r, gx0 = x0 - 12 + 4 * q;
    v4f v = {0.f, 0.f, 0.f, 0.f};
    if ((unsigned)gy < IMG) {
        const float* hr = &hmap[base + ((size_t)gy << 9)];
        if (gx0 >= 0 && gx0 + 3 < IMG) {
            v = *(const v4f*)&hr[gx0];
        } else {
            if ((unsigned)(gx0 + 0) < IMG) v.x = hr[gx0 + 0];
            if ((unsigned)(gx0 + 1) < IMG) v.y = hr[gx0 + 1];
            if ((unsigned)(gx0 + 2) < IMG) v.z = hr[gx0 + 2];
            if ((unsigned)(gx0 + 3) < IMG) v.w = hr[gx0 + 3];
        }
    }
    return v;
}

__global__ __launch_bounds__(256, 6) void marl_fused(
    const float* __restrict__ prob,
    const float* __restrict__ cmap,
    const float* __restrict__ hmap,
    float* __restrict__ out)
{
    __shared__ __align__(16) float Abuf[52 * A_STR];   // 3016 f: h tile, then ET[42][44]
    __shared__ __align__(16) float Bbuf[56 * BT_STR];  // 2576 f: BT, then CT[42][36]
    __shared__ float red[4];

    const float W[11] = {0.00881223f, 0.02714358f, 0.06511405f, 0.12164908f,
                         0.17699840f, 0.20056540f, 0.17699840f, 0.12164908f,
                         0.06511405f, 0.02714358f, 0.00881223f};
    v2f wv[11];
#pragma unroll
    for (int i = 0; i < 11; ++i) wv[i] = (v2f){W[i], W[i]};
    float w2 = 0.f;
#pragma unroll
    for (int i = 0; i < 11; ++i) w2 += W[i] * W[i];
    const float sumk2 = w2 * w2;
    const v2f z = {0.f, 0.f};

    const int tid = threadIdx.x;
    const int i0 = tid, i1 = tid + 256, i2 = tid + 512;

    // tile decode: 256 tiles/image (16 x 16)
    const int T  = blockIdx.x;
    const int b  = T >> 8, r8 = T & 255;
    const int x0 = (r8 & 15) * TS, y0 = (r8 >> 4) * TS;
    const size_t base = (size_t)b << 18;

    // P1 mapping: 98 workers, run fastest
    const int p1run = tid % 7, p1q = tid / 7;         // by0 = 6*p1run, cols 4*p1q
    // P2 mapping: 231 workers: p = ey-pair, eq = ex-quad
    const int p2p = tid % 21, p2eq = tid / 21;        // ey0 = 2*p2p, ex0 = 4*p2eq
    // P3 mapping: 168 workers: oy-octet fastest, then ex
    const int p3oyq = tid & 3, p3ex = tid >> 2;       // oy0 = 8*p3oyq
    // P4 mapping: all 256: lanes vary oy-pair (CT read stride 2 -> free)
    const int oy0e = 2 * (tid & 15), ox0 = 2 * (tid >> 4);

    // ---- prologue: stage h to LDS; c + epilogue h/prob to registers ----
    v2f hv[2], pv[2];
    float creg[2][4];
    {
        v4f ha = ldq(hmap, base, x0, y0, i0);
        v4f hb = ldq(hmap, base, x0, y0, i1);
        v4f hc = (tid < 216) ? ldq(hmap, base, x0, y0, i2) : (v4f){0.f,0.f,0.f,0.f};
        if (tid < 231) {
#pragma unroll
            for (int h = 0; h < 2; ++h) {
                int gy = y0 - 5 + 2 * p2p + h;
#pragma unroll
                for (int c = 0; c < 4; ++c) {
                    int gx = x0 - 5 + 4 * p2eq + c;
                    creg[h][c] = ((unsigned)gy < IMG && (unsigned)gx < IMG)
                        ? cmap[base + ((size_t)gy << 9) + gx] : 0.f;
                }
            }
        }
#pragma unroll
        for (int h = 0; h < 2; ++h) {
            size_t rowb = base + ((size_t)(y0 + oy0e + h) << 9) + (x0 + ox0);
            hv[h] = *(const v2f*)&hmap[rowb];
            pv[h] = *(const v2f*)&prob[rowb];
        }
        { int r = i0 / 14, q = i0 - r * 14; *(v4f*)&Abuf[r * A_STR + 4 * q] = ha; }
        { int r = i1 / 14, q = i1 - r * 14; *(v4f*)&Abuf[r * A_STR + 4 * q] = hb; }
        if (tid < 216) { int r = i2 / 14, q = i2 - r * 14; *(v4f*)&Abuf[r * A_STR + 4 * q] = hc; }
    }
    __syncthreads();

    // ---- P1: convY(h): Abuf[52][58] -> BT[56][46], 6 outs/worker ----
    if (tid < 98) {
        int by0 = 6 * p1run;
        v2f accLo[6] = {z, z, z, z, z, z}, accHi[6] = {z, z, z, z, z, z};
#pragma unroll
        for (int i = 0; i < 16; ++i) {
            v4f a = *(const v4f*)&Abuf[(by0 + i) * A_STR + 4 * p1q];
            v2f lo = lo2(a), hi = hi2(a);
#pragma unroll
            for (int r = 0; r < 6; ++r) {
                int j = i - r;
                if (j >= 0 && j < 11) { accLo[r] += wv[j] * lo; accHi[r] += wv[j] * hi; }
            }
        }
#pragma unroll
        for (int r = 0; r < 6; ++r) {
            int by = by0 + r;
            Bbuf[(4 * p1q + 0) * BT_STR + by] = accLo[r].x;
            Bbuf[(4 * p1q + 1) * BT_STR + by] = accLo[r].y;
            Bbuf[(4 * p1q + 2) * BT_STR + by] = accHi[r].x;
            Bbuf[(4 * p1q + 3) * BT_STR + by] = accHi[r].y;
        }
    }
    __syncthreads();

    // ---- P2: convX(BT) - c(regs) -> ET[42][44] transposed (overlays Abuf) ----
    if (tid < 231) {
        int ex0 = 4 * p2eq, ey0 = 2 * p2p;
        v2f acc[4] = {z, z, z, z};
#pragma unroll
        for (int i = 0; i < 14; ++i) {
            v2f bb = *(const v2f*)&Bbuf[(ex0 + 2 + i) * BT_STR + ey0];
#pragma unroll
            for (int c = 0; c < 4; ++c) {
                int j = i - c;
                if (j >= 0 && j < 11) acc[c] += wv[j] * bb;
            }
        }
#pragma unroll
        for (int c = 0; c < 4; ++c) {
            int ex = ex0 + c;
            if (ex < 42) {
                int gx = x0 - 5 + ex;
                bool xin = (unsigned)gx < IMG;
#pragma unroll
                for (int h = 0; h < 2; ++h) {
                    int gy = y0 - 5 + ey0 + h;
                    float v = 0.f;
                    if (xin && (unsigned)gy < IMG)
                        v = acc[c][h] - creg[h][c];
                    Abuf[ex * ET_STR + ey0 + h] = v;
                }
            }
        }
    }
    __syncthreads();

    // ---- P3: convY(ET) via register sliding window -> CT[42][36] ----
    if (tid < 168) {
        int oy0 = 8 * p3oyq;
        const float* src = &Abuf[p3ex * ET_STR + oy0];
        v4f w0 = *(const v4f*)&src[0];
        v4f w1 = *(const v4f*)&src[4];
        v4f w2_ = *(const v4f*)&src[8];
        v4f w3 = *(const v4f*)&src[12];
        v4f w4 = *(const v4f*)&src[16];
        float win[20];
        *(v4f*)&win[0] = w0; *(v4f*)&win[4] = w1; *(v4f*)&win[8] = w2_;
        *(v4f*)&win[12] = w3; *(v4f*)&win[16] = w4;
        float o[8];
#pragma unroll
        for (int k = 0; k < 8; ++k) {
            float acc = 0.f;
#pragma unroll
            for (int j = 0; j < 11; ++j) acc += W[j] * win[k + j];
            o[k] = acc;
        }
        *(v4f*)&Bbuf[p3ex * CT_STR + oy0]     = (v4f){o[0], o[1], o[2], o[3]};
        *(v4f*)&Bbuf[p3ex * CT_STR + oy0 + 4] = (v4f){o[4], o[5], o[6], o[7]};
    }
    __syncthreads();

    // ---- P4: convX(CT) -> corr + fused epilogue (all 256) ----
    float partial = 0.f;
    {
        v2f acc[2] = {z, z};
#pragma unroll
        for (int i = 0; i < 12; ++i) {
            v2f ct = *(const v2f*)&Bbuf[(ox0 + i) * CT_STR + oy0e];
#pragma unroll
            for (int c = 0; c < 2; ++c) {
                int j = i - c;
                if (j >= 0 && j < 11) acc[c] += wv[j] * ct;
            }
        }
#pragma unroll
        for (int h = 0; h < 2; ++h) {
#pragma unroll
            for (int c = 0; c < 2; ++c) {
                float h_ = hv[h][c], p_ = pv[h][c];
                float logp = __logf(h_ > 0.5f ? p_ + 1e-8f : 1.f - p_ + 1e-8f);
                float delta = 1.f - 2.f * h_;
                partial += (2.f * delta * acc[c][h] + sumk2) * logp;
            }
        }
    }

    // ---- reduction + one atomic per block ----
#pragma unroll
    for (int off = 32; off > 0; off >>= 1)
        partial += __shfl_down(partial, off, 64);
    if ((tid & 63) == 0) red[tid >> 6] = partial;
    __syncthreads();
    if (tid == 0) {
        float s = red[0] + red[1] + red[2] + red[3];
        atomicAdd(out, s * -0.125f);   // loss = -sum / B
    }
}

extern "C" void kernel_launch(void* const* d_in, const int* in_sizes, int n_in,
                              void* d_out, int out_size, void* d_ws, size_t ws_size,
                              hipStream_t stream) {
    const float* prob = (const float*)d_in[0];
    const float* cmap = (const float*)d_in[1];
    const float* hmap = (const float*)d_in[2];
    float* out = (float*)d_out;

    hipMemsetAsync(out, 0, sizeof(float), stream);

    marl_fused<<<dim3(NBLK), dim3(256), 0, stream>>>(prob, cmap, hmap, out);
}

// Round 12
// 83.151 us; speedup vs baseline: 1.2396x; 1.2396x over previous
//
#include <hip/hip_runtime.h>

typedef float v2f __attribute__((ext_vector_type(2)));
typedef float v4f __attribute__((ext_vector_type(4)));

#define IMG 512
#define NBLK 1024             // 64x32 tile per block: 8 x 16 tiles x 8 images

// LDS layouts (floats)
#define A_STR  92             // h tile [52][92]; gy=y0-10+r, gx=x0-12+c (c 0..87 used)
#define BT_STR 46             // BT [88][46]: BT[c][by], by 0..41 (gy=y0-5+by)
#define ET_STR 44             // ET [74][44]: ET[ex][ey]; gx=x0-5+ex; overlays Abuf
#define CT_STR 36             // CT [74][36]: CT[ex][oy], oy 0..31; overlays Bbuf

__device__ __forceinline__ v2f lo2(v4f v) { return __builtin_shufflevector(v, v, 0, 1); }
__device__ __forceinline__ v2f hi2(v4f v) { return __builtin_shufflevector(v, v, 2, 3); }

// one float4 of the h halo tile (zero-padded), quad index idx in [0,1144): 52 rows x 22 quads
__device__ __forceinline__ v4f ldq(const float* __restrict__ hmap, size_t base,
                                   int x0, int y0, int idx) {
    int r = idx / 22, q = idx - r * 22;
    int gy = y0 - 10 + r, gx0 = x0 - 12 + 4 * q;
    v4f v = {0.f, 0.f, 0.f, 0.f};
    if ((unsigned)gy < IMG) {
        const float* hr = &hmap[base + ((size_t)gy << 9)];
        if (gx0 >= 0 && gx0 + 3 < IMG) {
            v = *(const v4f*)&hr[gx0];
        } else {
            if ((unsigned)(gx0 + 0) < IMG) v.x = hr[gx0 + 0];
            if ((unsigned)(gx0 + 1) < IMG) v.y = hr[gx0 + 1];
            if ((unsigned)(gx0 + 2) < IMG) v.z = hr[gx0 + 2];
            if ((unsigned)(gx0 + 3) < IMG) v.w = hr[gx0 + 3];
        }
    }
    return v;
}

__global__ __launch_bounds__(256, 4) void marl_fused(
    const float* __restrict__ prob,
    const float* __restrict__ cmap,
    const float* __restrict__ hmap,
    float* __restrict__ ws)
{
    __shared__ __align__(16) float Abuf[52 * A_STR];   // 4784 f: h tile, then ET[74][44]
    __shared__ __align__(16) float Bbuf[88 * BT_STR];  // 4048 f: BT, then CT[74][36]
    __shared__ float red[4];

    const float W[11] = {0.00881223f, 0.02714358f, 0.06511405f, 0.12164908f,
                         0.17699840f, 0.20056540f, 0.17699840f, 0.12164908f,
                         0.06511405f, 0.02714358f, 0.00881223f};
    v2f wv[11];
#pragma unroll
    for (int i = 0; i < 11; ++i) wv[i] = (v2f){W[i], W[i]};
    float w2 = 0.f;
#pragma unroll
    for (int i = 0; i < 11; ++i) w2 += W[i] * W[i];
    const float sumk2 = w2 * w2;
    const v2f z = {0.f, 0.f};

    const int tid = threadIdx.x;
    // tile decode: 128 tiles/image (8 x, 16 y), 64x32 outputs
    const int T  = blockIdx.x;
    const int b  = T >> 7, r7 = T & 127;
    const int x0 = (r7 & 7) << 6, y0 = (r7 >> 3) << 5;
    const size_t base = (size_t)b << 18;

    // P1: 154 workers: q = tid/7 (col-quad 0..21), run = tid%7 (by0 = 6*run)
    const int p1run = tid % 7, p1q = tid / 7;
    // P2: 210 workers: p = tid%21 (ey-pair), exo = tid/21 (ex-oct 0..9)
    const int p2p = tid % 21, p2exo = tid / 21;
    // P3: 148 workers: ex = tid>>1, half = tid&1 (oy0 = 16*half)
    const int p3ex = tid >> 1, p3oy0 = (tid & 1) << 4;
    // P4: 256 workers: ox0 = 4*(tid>>4), oy0e = 2*(tid&15)
    const int ox0 = (tid >> 4) << 2, oy0e = (tid & 15) << 1;

    // ---- prologue: stage h tile (52x88 used cols) to LDS; c + epilogue h/prob to regs ----
    float creg[2][8];
    v4f hq[2], pq[2];
    {
        v4f s0 = ldq(hmap, base, x0, y0, tid);
        v4f s1 = ldq(hmap, base, x0, y0, tid + 256);
        v4f s2 = ldq(hmap, base, x0, y0, tid + 512);
        v4f s3 = ldq(hmap, base, x0, y0, tid + 768);
        v4f s4 = (tid < 120) ? ldq(hmap, base, x0, y0, tid + 1024) : (v4f){0.f,0.f,0.f,0.f};
        if (tid < 210) {
#pragma unroll
            for (int h = 0; h < 2; ++h) {
                int gy = y0 - 5 + 2 * p2p + h;
#pragma unroll
                for (int c = 0; c < 8; ++c) {
                    int gx = x0 - 5 + 8 * p2exo + c;
                    creg[h][c] = ((unsigned)gy < IMG && (unsigned)gx < IMG)
                        ? cmap[base + ((size_t)gy << 9) + gx] : 0.f;
                }
            }
        }
#pragma unroll
        for (int h = 0; h < 2; ++h) {
            size_t rowb = base + ((size_t)(y0 + oy0e + h) << 9) + (x0 + ox0);
            hq[h] = *(const v4f*)&hmap[rowb];
            pq[h] = *(const v4f*)&prob[rowb];
        }
        { int i = tid;       int r = i / 22, q = i - r * 22; *(v4f*)&Abuf[r * A_STR + 4 * q] = s0; }
        { int i = tid + 256; int r = i / 22, q = i - r * 22; *(v4f*)&Abuf[r * A_STR + 4 * q] = s1; }
        { int i = tid + 512; int r = i / 22, q = i - r * 22; *(v4f*)&Abuf[r * A_STR + 4 * q] = s2; }
        { int i = tid + 768; int r = i / 22, q = i - r * 22; *(v4f*)&Abuf[r * A_STR + 4 * q] = s3; }
        if (tid < 120) { int i = tid + 1024; int r = i / 22, q = i - r * 22;
                         *(v4f*)&Abuf[r * A_STR + 4 * q] = s4; }
    }
    __syncthreads();

    // ---- P1: convY(h): Abuf[52][92] -> BT[88][46], 6 outs/worker ----
    if (tid < 154) {
        int by0 = 6 * p1run;
        v2f accLo[6] = {z, z, z, z, z, z}, accHi[6] = {z, z, z, z, z, z};
#pragma unroll
        for (int i = 0; i < 16; ++i) {
            v4f a = *(const v4f*)&Abuf[(by0 + i) * A_STR + 4 * p1q];
            v2f lo = lo2(a), hi = hi2(a);
#pragma unroll
            for (int r = 0; r < 6; ++r) {
                int j = i - r;
                if (j >= 0 && j < 11) { accLo[r] += wv[j] * lo; accHi[r] += wv[j] * hi; }
            }
        }
#pragma unroll
        for (int r = 0; r < 6; ++r) {
            int by = by0 + r;
            Bbuf[(4 * p1q + 0) * BT_STR + by] = accLo[r].x;
            Bbuf[(4 * p1q + 1) * BT_STR + by] = accLo[r].y;
            Bbuf[(4 * p1q + 2) * BT_STR + by] = accHi[r].x;
            Bbuf[(4 * p1q + 3) * BT_STR + by] = accHi[r].y;
        }
    }
    __syncthreads();

    // ---- P2: convX(BT) - c(regs) -> ET[74][44] (overlays Abuf) ----
    if (tid < 210) {
        int ex0 = 8 * p2exo, ey0 = 2 * p2p;
        v2f acc[8] = {z, z, z, z, z, z, z, z};
#pragma unroll
        for (int i = 0; i < 18; ++i) {
            int cb = ex0 + 2 + i; cb = cb > 85 ? 85 : cb;   // clamp: clipped outs discard
            v2f bb = *(const v2f*)&Bbuf[cb * BT_STR + ey0];
#pragma unroll
            for (int c = 0; c < 8; ++c) {
                int j = i - c;
                if (j >= 0 && j < 11) acc[c] += wv[j] * bb;
            }
        }
#pragma unroll
        for (int c = 0; c < 8; ++c) {
            int ex = ex0 + c;
            if (ex < 74) {
                int gx = x0 - 5 + ex;
                bool xin = (unsigned)gx < IMG;
                v2f ev;
#pragma unroll
                for (int h = 0; h < 2; ++h) {
                    int gy = y0 - 5 + ey0 + h;
                    ev[h] = (xin && (unsigned)gy < IMG) ? acc[c][h] - creg[h][c] : 0.f;
                }
                *(v2f*)&Abuf[ex * ET_STR + ey0] = ev;
            }
        }
    }
    __syncthreads();

    // ---- P3: convY(ET) via register window -> CT[74][36], 16 outs/worker ----
    if (tid < 148) {
        const float* src = &Abuf[p3ex * ET_STR + p3oy0];
        float win[26];
#pragma unroll
        for (int k = 0; k < 6; ++k)
            *(v4f*)&win[4 * k] = *(const v4f*)&src[4 * k];
        *(v2f*)&win[24] = *(const v2f*)&src[24];
        float o[16];
#pragma unroll
        for (int k = 0; k < 16; ++k) {
            float acc = 0.f;
#pragma unroll
            for (int j = 0; j < 11; ++j) acc += W[j] * win[k + j];
            o[k] = acc;
        }
#pragma unroll
        for (int k = 0; k < 4; ++k)
            *(v4f*)&Bbuf[p3ex * CT_STR + p3oy0 + 4 * k] =
                (v4f){o[4 * k], o[4 * k + 1], o[4 * k + 2], o[4 * k + 3]};
    }
    __syncthreads();

    // ---- P4: convX(CT) -> corr + fused epilogue (all 256, 8 outs each) ----
    float partial = 0.f;
    {
        v2f acc[4] = {z, z, z, z};
#pragma unroll
        for (int i = 0; i < 14; ++i) {
            v2f ct = *(const v2f*)&Bbuf[(ox0 + i) * CT_STR + oy0e];
#pragma unroll
            for (int c = 0; c < 4; ++c) {
                int j = i - c;
                if (j >= 0 && j < 11) acc[c] += wv[j] * ct;
            }
        }
#pragma unroll
        for (int h = 0; h < 2; ++h) {
#pragma unroll
            for (int c = 0; c < 4; ++c) {
                float h_ = hq[h][c], p_ = pq[h][c];
                float logp = __logf(h_ > 0.5f ? p_ + 1e-8f : 1.f - p_ + 1e-8f);
                float delta = 1.f - 2.f * h_;
                partial += (2.f * delta * acc[c][h] + sumk2) * logp;
            }
        }
    }

    // ---- reduction -> per-block partial in ws ----
#pragma unroll
    for (int off = 32; off > 0; off >>= 1)
        partial += __shfl_down(partial, off, 64);
    if ((tid & 63) == 0) red[tid >> 6] = partial;
    __syncthreads();
    if (tid == 0)
        ws[blockIdx.x] = red[0] + red[1] + red[2] + red[3];
}

__global__ __launch_bounds__(256) void marl_reduce(const float* __restrict__ ws,
                                                   float* __restrict__ out)
{
    __shared__ float red[4];
    const int tid = threadIdx.x;
    float s = ws[tid] + ws[tid + 256] + ws[tid + 512] + ws[tid + 768];
#pragma unroll
    for (int off = 32; off > 0; off >>= 1)
        s += __shfl_down(s, off, 64);
    if ((tid & 63) == 0) red[tid >> 6] = s;
    __syncthreads();
    if (tid == 0)
        out[0] = -0.125f * (red[0] + red[1] + red[2] + red[3]);  // loss = -sum / B
}

extern "C" void kernel_launch(void* const* d_in, const int* in_sizes, int n_in,
                              void* d_out, int out_size, void* d_ws, size_t ws_size,
                              hipStream_t stream) {
    const float* prob = (const float*)d_in[0];
    const float* cmap = (const float*)d_in[1];
    const float* hmap = (const float*)d_in[2];
    float* out = (float*)d_out;
    float* ws  = (float*)d_ws;

    marl_fused<<<dim3(NBLK), dim3(256), 0, stream>>>(prob, cmap, hmap, ws);
    marl_reduce<<<dim3(1), dim3(256), 0, stream>>>(ws, out);
}